// Round 2
// baseline (29994.623 us; speedup 1.0000x reference)
//
#include <hip/hip_runtime.h>
#include <math.h>

// Problem constants (match reference)
#define BB   16384
#define NOBS 512
#define NACT 64
#define DIN  1090      // 512+64+512+1+1
#define K0P  1120      // DIN padded to multiple of 16 (zeros)
#define HH   4096
#define DD   1024
#define KC   512

#define MC   2048      // batch chunk rows for the MLP
#define NCH  (BB / MC) // 8 chunks

#define F_DECAY 0.99f
#define F_OMD   0.01f
#define F_CC    0.25f
#define F_EPS   1e-5f

// ------------------------------------------------------------------
// Build one chunk of X0 = hstack(obs, action, next_obs, reward, term), padded.
// Pointers are pre-offset to the chunk start; grid = MC blocks.
// ------------------------------------------------------------------
__global__ __launch_bounds__(256) void build_x0_kernel(
    const float* __restrict__ obs, const float* __restrict__ act,
    const float* __restrict__ nobs, const float* __restrict__ rew,
    const float* __restrict__ term, float* __restrict__ X0)
{
  const int i = blockIdx.x;      // row within chunk
  const int t = threadIdx.x;
  float* row = X0 + (size_t)i * K0P;
  for (int c = t; c < K0P; c += 256) {
    float v;
    if (c < NOBS)                 v = obs[(size_t)i * NOBS + c];
    else if (c < NOBS + NACT)     v = act[(size_t)i * NACT + (c - NOBS)];
    else if (c < 2*NOBS + NACT)   v = nobs[(size_t)i * NOBS + (c - NOBS - NACT)];
    else if (c == 1088)           v = rew[i];
    else if (c == 1089)           v = term[i];
    else                          v = 0.0f;
    row[c] = v;
  }
}

// ------------------------------------------------------------------
// zero histogram + loss accumulator (run AFTER the MLP loop: these live
// in a region that the MLP buffers overlay)
// ------------------------------------------------------------------
__global__ void init_kernel(int* __restrict__ cnt, float* __restrict__ lsum)
{
  const int t = threadIdx.x;
  if (t < KC) cnt[t] = 0;
  if (t == 0) *lsum = 0.0f;
}

// ------------------------------------------------------------------
// fp32 tiled GEMM: C[m,n] = act(alpha * sum_k A[m,k]*W[k,n] + bias[n])
// A: [M,K] row-major (lda == K), W: [K,N] row-major, bias: [N]
// BM=BN=128, BK=16, 256 threads, 8x8 per thread (2x2 blocks of 4x4).
// Rows k >= Kreal of W are treated as zero (layer0: Kreal=1090 < K=1120).
// ------------------------------------------------------------------
template<bool RELU>
__global__ __launch_bounds__(256) void sgemm_kernel(
    const float* __restrict__ A, const float* __restrict__ W,
    const float* __restrict__ bias, float* __restrict__ C,
    int M, int N, int K, int Kreal, float alpha)
{
  __shared__ float As[16][128];   // [kk][m]
  __shared__ float Bs[16][128];   // [kk][n]

  const int tid = threadIdx.x;
  const int n0 = blockIdx.x * 128;
  const int m0 = blockIdx.y * 128;

  const int ar = tid & 63;                // A rows ar, ar+64
  const int ak = (tid >> 6) << 2;         // 0,4,8,12
  const int bk = tid >> 5;                // 0..7 (k-rows bk, bk+8)
  const int bc = (tid & 31) << 2;         // 0..124

  const int tx = tid & 15;
  const int ty = tid >> 4;

  float acc[2][2][4][4];
  #pragma unroll
  for (int a = 0; a < 2; ++a)
    #pragma unroll
    for (int b = 0; b < 2; ++b)
      #pragma unroll
      for (int c = 0; c < 4; ++c)
        #pragma unroll
        for (int d = 0; d < 4; ++d) acc[a][b][c][d] = 0.0f;

  const float4 zero4 = make_float4(0.f, 0.f, 0.f, 0.f);

  for (int k0 = 0; k0 < K; k0 += 16) {
    float4 a0 = *(const float4*)(A + (size_t)(m0 + ar) * K + k0 + ak);
    float4 a1 = *(const float4*)(A + (size_t)(m0 + ar + 64) * K + k0 + ak);
    const int kr0 = k0 + bk, kr1 = k0 + bk + 8;
    float4 b0 = (kr0 < Kreal) ? *(const float4*)(W + (size_t)kr0 * N + n0 + bc) : zero4;
    float4 b1 = (kr1 < Kreal) ? *(const float4*)(W + (size_t)kr1 * N + n0 + bc) : zero4;

    __syncthreads();
    As[ak + 0][ar] = a0.x; As[ak + 1][ar] = a0.y;
    As[ak + 2][ar] = a0.z; As[ak + 3][ar] = a0.w;
    As[ak + 0][ar + 64] = a1.x; As[ak + 1][ar + 64] = a1.y;
    As[ak + 2][ar + 64] = a1.z; As[ak + 3][ar + 64] = a1.w;
    *(float4*)&Bs[bk][bc]     = b0;
    *(float4*)&Bs[bk + 8][bc] = b1;
    __syncthreads();

    #pragma unroll
    for (int kk = 0; kk < 16; ++kk) {
      const float4 av0 = *(const float4*)&As[kk][ty * 4];
      const float4 av1 = *(const float4*)&As[kk][ty * 4 + 64];
      const float4 bv0 = *(const float4*)&Bs[kk][tx * 4];
      const float4 bv1 = *(const float4*)&Bs[kk][tx * 4 + 64];
      const float am[2][4] = {{av0.x, av0.y, av0.z, av0.w}, {av1.x, av1.y, av1.z, av1.w}};
      const float bn[2][4] = {{bv0.x, bv0.y, bv0.z, bv0.w}, {bv1.x, bv1.y, bv1.z, bv1.w}};
      #pragma unroll
      for (int mi = 0; mi < 2; ++mi)
        #pragma unroll
        for (int ni = 0; ni < 2; ++ni)
          #pragma unroll
          for (int mj = 0; mj < 4; ++mj)
            #pragma unroll
            for (int nj = 0; nj < 4; ++nj)
              acc[mi][ni][mj][nj] += am[mi][mj] * bn[ni][nj];
    }
  }

  const float4 bi0 = *(const float4*)(bias + n0 + tx * 4);
  const float4 bi1 = *(const float4*)(bias + n0 + tx * 4 + 64);
  const float bb[2][4] = {{bi0.x, bi0.y, bi0.z, bi0.w}, {bi1.x, bi1.y, bi1.z, bi1.w}};

  #pragma unroll
  for (int mi = 0; mi < 2; ++mi)
    #pragma unroll
    for (int mj = 0; mj < 4; ++mj) {
      const int m = m0 + mi * 64 + ty * 4 + mj;
      #pragma unroll
      for (int ni = 0; ni < 2; ++ni) {
        float4 o;
        o.x = alpha * acc[mi][ni][mj][0] + bb[ni][0];
        o.y = alpha * acc[mi][ni][mj][1] + bb[ni][1];
        o.z = alpha * acc[mi][ni][mj][2] + bb[ni][2];
        o.w = alpha * acc[mi][ni][mj][3] + bb[ni][3];
        if (RELU) {
          o.x = fmaxf(o.x, 0.f); o.y = fmaxf(o.y, 0.f);
          o.z = fmaxf(o.z, 0.f); o.w = fmaxf(o.w, 0.f);
        }
        *(float4*)(C + (size_t)m * N + n0 + ni * 64 + tx * 4) = o;
      }
    }
}

// ------------------------------------------------------------------
// esq[k] = sum_d emb[d,k]^2     (emb is [D,K] row-major)
// ------------------------------------------------------------------
__global__ __launch_bounds__(512) void esq_kernel(const float* __restrict__ emb,
                                                  float* __restrict__ esq)
{
  const int k = threadIdx.x;
  float s = 0.0f;
  for (int d = 0; d < DD; ++d) { const float v = emb[(size_t)d * KC + k]; s += v * v; }
  esq[k] = s;
}

// embT[k,d] = emb[d,k]
__global__ __launch_bounds__(256) void transpose_kernel(const float* __restrict__ emb,
                                                        float* __restrict__ embT)
{
  const int t = blockIdx.x * 256 + threadIdx.x;   // t = k*DD + d
  const int d = t & (DD - 1);
  const int k = t >> 10;
  embT[t] = emb[(size_t)d * KC + k];
}

// ------------------------------------------------------------------
// argmin per row of S [B,KC] (S = esq[k] - 2*z.e_k), np first-index ties.
// One wave per row. Also builds the histogram.
// ------------------------------------------------------------------
__global__ __launch_bounds__(64) void argmin_kernel(const float* __restrict__ S,
                                                    int* __restrict__ idx,
                                                    int* __restrict__ cnt)
{
  const int i = blockIdx.x;
  const int lane = threadIdx.x;
  const float* row = S + (size_t)i * KC;
  float best = 3.4e38f;
  int   bi   = 0x7fffffff;
  for (int k = lane; k < KC; k += 64) {       // ascending per lane -> strict <
    const float v = row[k];
    if (v < best) { best = v; bi = k; }
  }
  #pragma unroll
  for (int off = 32; off > 0; off >>= 1) {
    const float ov = __shfl_down(best, off);
    const int   oi = __shfl_down(bi, off);
    if (ov < best || (ov == best && oi < bi)) { best = ov; bi = oi; }
  }
  if (lane == 0) { idx[i] = bi; atomicAdd(cnt + bi, 1); }
}

// ------------------------------------------------------------------
// cs_stable + perplexity (needs only cnt/ecs; loss comes later)
// ------------------------------------------------------------------
__global__ __launch_bounds__(512) void finalize_cs_kernel(const int* __restrict__ cnt,
    const float* __restrict__ ecs,
    float* __restrict__ out_perp, float* __restrict__ out_cs, float* __restrict__ ws_cs)
{
  const int t = threadIdx.x;     // 512 == KC
  __shared__ float red[512];
  const float c  = (float)cnt[t];
  const float cs = F_DECAY * ecs[t] + F_OMD * c;
  red[t] = cs; __syncthreads();
  for (int s = 256; s > 0; s >>= 1) { if (t < s) red[t] += red[t + s]; __syncthreads(); }
  const float n = red[0]; __syncthreads();
  const float css = (cs + F_EPS) / (n + (float)KC * F_EPS) * n;
  out_cs[t] = css;
  ws_cs[t]  = css;
  const float p = c * (1.0f / (float)BB);
  red[t] = p * logf(p + 1e-10f); __syncthreads();
  for (int s = 256; s > 0; s >>= 1) { if (t < s) red[t] += red[t + s]; __syncthreads(); }
  if (t == 0) *out_perp = expf(-red[0]);
}

__global__ void finalize_loss_kernel(const float* __restrict__ lsum,
                                     float* __restrict__ out_loss)
{
  *out_loss = F_CC * lsum[0] * (1.0f / ((float)BB * (float)DD));
}

// ------------------------------------------------------------------
// new_embeddings[d,k] = (DECAY*ema_dw[d,k] + 0.01*sum_{i:idx=k} z[i,d]) / cs_stable[k]
// One block per codebook k; deterministic chunked scan of idx.
// ------------------------------------------------------------------
__global__ __launch_bounds__(256) void dw_kernel(const int* __restrict__ idx,
    const float* __restrict__ z, const float* __restrict__ ema_dw,
    const float* __restrict__ ws_cs, float* __restrict__ out_emb)
{
  const int k = blockIdx.x;     // 0..KC-1
  const int t = threadIdx.x;    // 256; owns d = t, t+256, t+512, t+768
  __shared__ int chunk[256];
  float a0 = 0.f, a1 = 0.f, a2 = 0.f, a3 = 0.f;
  for (int i0 = 0; i0 < BB; i0 += 256) {
    __syncthreads();
    chunk[t] = idx[i0 + t];
    __syncthreads();
    for (int j = 0; j < 256; ++j) {
      if (chunk[j] == k) {                    // block-uniform branch
        const float* zr = z + (size_t)(i0 + j) * DD;
        a0 += zr[t]; a1 += zr[t + 256]; a2 += zr[t + 512]; a3 += zr[t + 768];
      }
    }
  }
  const float inv = 1.0f / ws_cs[k];
  out_emb[(size_t)(t      ) * KC + k] = (F_DECAY * ema_dw[(size_t)(t      ) * KC + k] + F_OMD * a0) * inv;
  out_emb[(size_t)(t + 256) * KC + k] = (F_DECAY * ema_dw[(size_t)(t + 256) * KC + k] + F_OMD * a1) * inv;
  out_emb[(size_t)(t + 512) * KC + k] = (F_DECAY * ema_dw[(size_t)(t + 512) * KC + k] + F_OMD * a2) * inv;
  out_emb[(size_t)(t + 768) * KC + k] = (F_DECAY * ema_dw[(size_t)(t + 768) * KC + k] + F_OMD * a3) * inv;
}

// ------------------------------------------------------------------
// q_st gather IN PLACE over z (zq both read and written; same addresses
// per thread, read-before-write, deliberately NOT __restrict__).
// Also accumulates sum((q - z)^2) into lsum.
// ------------------------------------------------------------------
__global__ __launch_bounds__(256) void gather_kernel(const int* __restrict__ idx,
    const float* __restrict__ embT, float* zq, float* __restrict__ lsum)
{
  const int i = blockIdx.x;
  const int t = threadIdx.x;
  const int id = idx[i];
  const float4 q  = *(const float4*)(embT + (size_t)id * DD + t * 4);
  const float4 zv = *(const float4*)(zq   + (size_t)i  * DD + t * 4);
  *(float4*)(zq + (size_t)i * DD + t * 4) = q;
  const float dx = q.x - zv.x, dy = q.y - zv.y, dz = q.z - zv.z, dw = q.w - zv.w;
  float s = dx * dx + dy * dy + dz * dz + dw * dw;

  __shared__ float red[256];
  red[t] = s; __syncthreads();
  for (int st = 128; st > 0; st >>= 1) { if (t < st) red[t] += red[t + st]; __syncthreads(); }
  if (t == 0) atomicAdd(lsum, red[0]);
}

// ------------------------------------------------------------------
extern "C" void kernel_launch(void* const* d_in, const int* in_sizes, int n_in,
                              void* d_out, int out_size, void* d_ws, size_t ws_size,
                              hipStream_t stream)
{
  const float* obs  = (const float*)d_in[0];
  const float* act  = (const float*)d_in[1];
  const float* nobs = (const float*)d_in[2];
  const float* rew  = (const float*)d_in[3];
  const float* term = (const float*)d_in[4];
  const float* w0 = (const float*)d_in[5];  const float* b0 = (const float*)d_in[6];
  const float* w1 = (const float*)d_in[7];  const float* b1 = (const float*)d_in[8];
  const float* w2 = (const float*)d_in[9];  const float* b2 = (const float*)d_in[10];
  const float* w3 = (const float*)d_in[11]; const float* b3 = (const float*)d_in[12];
  const float* wl = (const float*)d_in[13]; const float* bl = (const float*)d_in[14];
  const float* emb = (const float*)d_in[15];
  const float* ecs = (const float*)d_in[16];
  const float* edw = (const float*)d_in[17];
  // d_in[18] = is_training (reference computes the same graph regardless)

  // ---- workspace layout (floats) — total 19,070,976 floats = 72.8 MiB ----
  float* ws   = (float*)d_ws;
  float* bufX = ws;                               // MC*K0P  = 2,293,760
  float* bufA = bufX + (size_t)MC * K0P;          // MC*HH   = 8,388,608
  float* bufB = bufA + (size_t)MC * HH;           // MC*HH   = 8,388,608
  // post-MLP overlays:
  float* S    = bufA;                             // BB*KC = 8,388,608 (exact fit)
  float* esq  = bufB;                             // KC
  float* embT = esq + KC;                         // KC*DD = 524,288
  int*   idx  = (int*)(embT + (size_t)KC * DD);   // BB ints
  int*   cnt  = idx + BB;                         // KC ints
  float* lsum = (float*)(cnt + KC);               // 1
  float* wcs  = lsum + 1;                         // KC   (tail total 542,209 < 8,388,608)

  float* out      = (float*)d_out;
  float* zq       = out;                          // z lives here, gather overwrites with q_st
  float* out_loss = out + (size_t)BB * DD;        // 1
  float* out_perp = out_loss + 1;                 // 1
  float* out_emb  = out_perp + 1;                 // DD*KC
  float* out_cs   = out_emb + (size_t)DD * KC;    // KC

  const dim3 blk(256);

  // ---- MLP in batch chunks of MC rows ----
  for (int c = 0; c < NCH; ++c) {
    const size_t c0 = (size_t)c * MC;
    build_x0_kernel<<<dim3(MC), blk, 0, stream>>>(obs + c0 * NOBS, act + c0 * NACT,
                                                  nobs + c0 * NOBS, rew + c0, term + c0, bufX);
    sgemm_kernel<true ><<<dim3(HH / 128, MC / 128), blk, 0, stream>>>(bufX, w0, b0, bufA, MC, HH, K0P, DIN, 1.0f);
    sgemm_kernel<true ><<<dim3(HH / 128, MC / 128), blk, 0, stream>>>(bufA, w1, b1, bufB, MC, HH, HH,  HH,  1.0f);
    sgemm_kernel<true ><<<dim3(HH / 128, MC / 128), blk, 0, stream>>>(bufB, w2, b2, bufA, MC, HH, HH,  HH,  1.0f);
    sgemm_kernel<true ><<<dim3(HH / 128, MC / 128), blk, 0, stream>>>(bufA, w3, b3, bufB, MC, HH, HH,  HH,  1.0f);
    sgemm_kernel<false><<<dim3(DD / 128, MC / 128), blk, 0, stream>>>(bufB, wl, bl, zq + c0 * DD, MC, DD, HH, HH, 1.0f);
  }

  // ---- VQ phase (init AFTER the MLP: cnt/lsum live under the bufB overlay) ----
  init_kernel<<<1, 512, 0, stream>>>(cnt, lsum);
  esq_kernel<<<1, 512, 0, stream>>>(emb, esq);
  sgemm_kernel<false><<<dim3(KC / 128, BB / 128), blk, 0, stream>>>(zq, emb, esq, S, BB, KC, DD, DD, -2.0f);
  argmin_kernel<<<dim3(BB), dim3(64), 0, stream>>>(S, idx, cnt);
  finalize_cs_kernel<<<1, 512, 0, stream>>>(cnt, ecs, out_perp, out_cs, wcs);
  dw_kernel<<<dim3(KC), blk, 0, stream>>>(idx, zq, edw, wcs, out_emb);      // reads z
  transpose_kernel<<<dim3((KC * DD) / 256), blk, 0, stream>>>(emb, embT);
  gather_kernel<<<dim3(BB), blk, 0, stream>>>(idx, embT, zq, lsum);         // z -> q_st in place
  finalize_loss_kernel<<<1, 1, 0, stream>>>(lsum, out_loss);
}

// Round 3
// 18100.275 us; speedup vs baseline: 1.6571x; 1.6571x over previous
//
#include <hip/hip_runtime.h>
#include <math.h>

// Problem constants (match reference)
#define BB   16384
#define NOBS 512
#define NACT 64
#define DIN  1090      // 512+64+512+1+1
#define K0P  1120      // DIN padded to multiple of 32 (zeros)
#define HH   4096
#define DD   1024
#define KC   512

#define MC   2048      // batch chunk rows for the MLP
#define NCH  (BB / MC) // 8 chunks

#define F_DECAY 0.99f
#define F_OMD   0.01f
#define F_CC    0.25f
#define F_EPS   1e-5f

using s8v  = __attribute__((ext_vector_type(8))) short;   // 8 bf16 (4 VGPRs) MFMA A/B frag
using s4v  = __attribute__((ext_vector_type(4))) short;   // 4 bf16 (8B LDS store)
using f4v  = __attribute__((ext_vector_type(4))) float;   // MFMA C/D frag

// ---- fp32 -> bf16 (RNE) bit ops + exact 3-way split ----
static __device__ inline unsigned short f2bf(float f) {
  unsigned u = __float_as_uint(f);
  u += 0x7fff + ((u >> 16) & 1);
  return (unsigned short)(u >> 16);
}
static __device__ inline float bf2f(unsigned short h) {
  return __uint_as_float(((unsigned)h) << 16);
}
static __device__ inline void split3(float x, unsigned short& h, unsigned short& m,
                                     unsigned short& l) {
  h = f2bf(x);  const float r1 = x - bf2f(h);   // exact
  m = f2bf(r1); const float r2 = r1 - bf2f(m);  // exact
  l = f2bf(r2);
}

// ------------------------------------------------------------------
// Build one chunk of X0 = hstack(obs, action, next_obs, reward, term), padded.
// ------------------------------------------------------------------
__global__ __launch_bounds__(256) void build_x0_kernel(
    const float* __restrict__ obs, const float* __restrict__ act,
    const float* __restrict__ nobs, const float* __restrict__ rew,
    const float* __restrict__ term, float* __restrict__ X0)
{
  const int i = blockIdx.x;
  const int t = threadIdx.x;
  float* row = X0 + (size_t)i * K0P;
  for (int c = t; c < K0P; c += 256) {
    float v;
    if (c < NOBS)                 v = obs[(size_t)i * NOBS + c];
    else if (c < NOBS + NACT)     v = act[(size_t)i * NACT + (c - NOBS)];
    else if (c < 2*NOBS + NACT)   v = nobs[(size_t)i * NOBS + (c - NOBS - NACT)];
    else if (c == 1088)           v = rew[i];
    else if (c == 1089)           v = term[i];
    else                          v = 0.0f;
    row[c] = v;
  }
}

__global__ void init_kernel(int* __restrict__ cnt, float* __restrict__ lsum)
{
  const int t = threadIdx.x;
  if (t < KC) cnt[t] = 0;
  if (t == 0) *lsum = 0.0f;
}

// ------------------------------------------------------------------
// Emulated-fp32 GEMM via bf16x3 split + MFMA (6 products):
// C[m,n] = act( sum_k A[m,k]*W[k,n] + bias[n] )
// A: [M,K] fp32 row-major, W: [K,N] fp32 row-major (rows >= Kreal read as 0).
// BM=BN=128, BK=32, 256 threads (4 waves, 2x2), wave tile 64x64 =
// 4x4 of 16x16x32 MFMA tiles. LDS: [comp][kgroup][row][8] bf16, k-contiguous
// per lane (16B/lane ds_read_b128, conflict-free).
// ------------------------------------------------------------------
template<bool RELU>
__global__ __launch_bounds__(256, 2) void gemm_bf16x3_kernel(
    const float* __restrict__ A, const float* __restrict__ W,
    const float* __restrict__ bias, float* __restrict__ C,
    int M, int N, int K, int Kreal)
{
  __shared__ __align__(16) short Alds[3][4][128][8];   // 24 KB
  __shared__ __align__(16) short Blds[3][4][128][8];   // 24 KB

  const int tid = threadIdx.x;
  const int n0 = blockIdx.x * 128;
  const int m0 = blockIdx.y * 128;

  // staging maps
  const int sam = tid >> 1;          // A row 0..127
  const int sah = tid & 1;           // A k-half (16 floats each)
  const int sbn = tid & 127;         // B col 0..127
  const int sbq = tid >> 7;          // B k-half

  // compute maps
  const int lane = tid & 63;
  const int wv   = tid >> 6;             // wave 0..3 (2x2)
  const int wmo  = (wv >> 1) * 64;
  const int wno  = (wv & 1) * 64;
  const int lm   = lane & 15;            // m (A) / n (B) / col (C)
  const int kg   = lane >> 4;            // k-group 0..3 (8 k each)

  f4v acc[4][4];
  #pragma unroll
  for (int a = 0; a < 4; ++a)
    #pragma unroll
    for (int b = 0; b < 4; ++b) acc[a][b] = (f4v)0.0f;

  for (int k0 = 0; k0 < K; k0 += 32) {
    // ---- global loads (regs) ----
    float4 av[4];
    #pragma unroll
    for (int q = 0; q < 4; ++q)
      av[q] = *(const float4*)(A + (size_t)(m0 + sam) * K + k0 + sah * 16 + q * 4);
    float bv[16];
    #pragma unroll
    for (int i = 0; i < 16; ++i) {
      const int kk = k0 + sbq * 16 + i;
      bv[i] = (kk < Kreal) ? W[(size_t)kk * N + n0 + sbn] : 0.0f;
    }

    __syncthreads();   // previous iteration's LDS reads complete

    // ---- split + stage A: 4 x (3 comps x ds_write_b64) ----
    #pragma unroll
    for (int q = 0; q < 4; ++q) {
      const float xs[4] = {av[q].x, av[q].y, av[q].z, av[q].w};
      s4v hh, mm, ll;
      #pragma unroll
      for (int j = 0; j < 4; ++j) {
        unsigned short h, m, l; split3(xs[j], h, m, l);
        hh[j] = (short)h; mm[j] = (short)m; ll[j] = (short)l;
      }
      const int kgi = sah * 2 + (q >> 1);
      const int j0  = (q & 1) * 4;
      *(s4v*)&Alds[0][kgi][sam][j0] = hh;
      *(s4v*)&Alds[1][kgi][sam][j0] = mm;
      *(s4v*)&Alds[2][kgi][sam][j0] = ll;
    }
    // ---- split + stage B: 2 groups x (3 comps x ds_write_b128) ----
    unsigned short bh[16], bm[16], bl[16];
    #pragma unroll
    for (int i = 0; i < 16; ++i) split3(bv[i], bh[i], bm[i], bl[i]);
    #pragma unroll
    for (int g = 0; g < 2; ++g) {
      s8v vh, vm, vl;
      #pragma unroll
      for (int j = 0; j < 8; ++j) {
        vh[j] = (short)bh[g * 8 + j]; vm[j] = (short)bm[g * 8 + j]; vl[j] = (short)bl[g * 8 + j];
      }
      const int kgi = sbq * 2 + g;
      *(s8v*)&Blds[0][kgi][sbn][0] = vh;
      *(s8v*)&Blds[1][kgi][sbn][0] = vm;
      *(s8v*)&Blds[2][kgi][sbn][0] = vl;
    }
    __syncthreads();

    // ---- compute: hold all B frags, loop A m-tiles ----
    s8v bf[3][4];
    #pragma unroll
    for (int nt = 0; nt < 4; ++nt) {
      bf[0][nt] = *(const s8v*)&Blds[0][kg][wno + nt * 16 + lm][0];
      bf[1][nt] = *(const s8v*)&Blds[1][kg][wno + nt * 16 + lm][0];
      bf[2][nt] = *(const s8v*)&Blds[2][kg][wno + nt * 16 + lm][0];
    }
    #pragma unroll
    for (int mt = 0; mt < 4; ++mt) {
      const s8v ah = *(const s8v*)&Alds[0][kg][wmo + mt * 16 + lm][0];
      const s8v am = *(const s8v*)&Alds[1][kg][wmo + mt * 16 + lm][0];
      const s8v al = *(const s8v*)&Alds[2][kg][wmo + mt * 16 + lm][0];
      #pragma unroll
      for (int nt = 0; nt < 4; ++nt) {
        f4v a = acc[mt][nt];
        a = __builtin_amdgcn_mfma_f32_16x16x32_bf16(ah, bf[0][nt], a, 0, 0, 0); // hi*hi
        a = __builtin_amdgcn_mfma_f32_16x16x32_bf16(ah, bf[1][nt], a, 0, 0, 0); // hi*mid
        a = __builtin_amdgcn_mfma_f32_16x16x32_bf16(am, bf[0][nt], a, 0, 0, 0); // mid*hi
        a = __builtin_amdgcn_mfma_f32_16x16x32_bf16(ah, bf[2][nt], a, 0, 0, 0); // hi*lo
        a = __builtin_amdgcn_mfma_f32_16x16x32_bf16(al, bf[0][nt], a, 0, 0, 0); // lo*hi
        a = __builtin_amdgcn_mfma_f32_16x16x32_bf16(am, bf[1][nt], a, 0, 0, 0); // mid*mid
        acc[mt][nt] = a;
      }
    }
  }

  // ---- epilogue: C/D layout col=lane&15, row=(lane>>4)*4+reg ----
  float bias_v[4];
  #pragma unroll
  for (int nt = 0; nt < 4; ++nt) bias_v[nt] = bias[n0 + wno + nt * 16 + lm];

  #pragma unroll
  for (int mt = 0; mt < 4; ++mt)
    #pragma unroll
    for (int nt = 0; nt < 4; ++nt) {
      const int n = n0 + wno + nt * 16 + lm;
      #pragma unroll
      for (int r = 0; r < 4; ++r) {
        const int m = m0 + wmo + mt * 16 + kg * 4 + r;
        float v = acc[mt][nt][r] + bias_v[nt];
        if (RELU) v = fmaxf(v, 0.0f);
        C[(size_t)m * N + n] = v;
      }
    }
}

// ------------------------------------------------------------------
// fp32 vector GEMM (kept for the small scores GEMM only):
// C[m,n] = alpha * sum_k A[m,k]*W[k,n] + bias[n]
// ------------------------------------------------------------------
__global__ __launch_bounds__(256) void sgemm_kernel(
    const float* __restrict__ A, const float* __restrict__ W,
    const float* __restrict__ bias, float* __restrict__ C,
    int M, int N, int K, int Kreal, float alpha)
{
  __shared__ float As[16][128];
  __shared__ float Bs[16][128];

  const int tid = threadIdx.x;
  const int n0 = blockIdx.x * 128;
  const int m0 = blockIdx.y * 128;

  const int ar = tid & 63;
  const int ak = (tid >> 6) << 2;
  const int bk = tid >> 5;
  const int bc = (tid & 31) << 2;
  const int tx = tid & 15;
  const int ty = tid >> 4;

  float acc[2][2][4][4];
  #pragma unroll
  for (int a = 0; a < 2; ++a)
    #pragma unroll
    for (int b = 0; b < 2; ++b)
      #pragma unroll
      for (int c = 0; c < 4; ++c)
        #pragma unroll
        for (int d = 0; d < 4; ++d) acc[a][b][c][d] = 0.0f;

  const float4 zero4 = make_float4(0.f, 0.f, 0.f, 0.f);

  for (int k0 = 0; k0 < K; k0 += 16) {
    float4 a0 = *(const float4*)(A + (size_t)(m0 + ar) * K + k0 + ak);
    float4 a1 = *(const float4*)(A + (size_t)(m0 + ar + 64) * K + k0 + ak);
    const int kr0 = k0 + bk, kr1 = k0 + bk + 8;
    float4 b0 = (kr0 < Kreal) ? *(const float4*)(W + (size_t)kr0 * N + n0 + bc) : zero4;
    float4 b1 = (kr1 < Kreal) ? *(const float4*)(W + (size_t)kr1 * N + n0 + bc) : zero4;

    __syncthreads();
    As[ak + 0][ar] = a0.x; As[ak + 1][ar] = a0.y;
    As[ak + 2][ar] = a0.z; As[ak + 3][ar] = a0.w;
    As[ak + 0][ar + 64] = a1.x; As[ak + 1][ar + 64] = a1.y;
    As[ak + 2][ar + 64] = a1.z; As[ak + 3][ar + 64] = a1.w;
    *(float4*)&Bs[bk][bc]     = b0;
    *(float4*)&Bs[bk + 8][bc] = b1;
    __syncthreads();

    #pragma unroll
    for (int kk = 0; kk < 16; ++kk) {
      const float4 av0 = *(const float4*)&As[kk][ty * 4];
      const float4 av1 = *(const float4*)&As[kk][ty * 4 + 64];
      const float4 bv0 = *(const float4*)&Bs[kk][tx * 4];
      const float4 bv1 = *(const float4*)&Bs[kk][tx * 4 + 64];
      const float am[2][4] = {{av0.x, av0.y, av0.z, av0.w}, {av1.x, av1.y, av1.z, av1.w}};
      const float bn[2][4] = {{bv0.x, bv0.y, bv0.z, bv0.w}, {bv1.x, bv1.y, bv1.z, bv1.w}};
      #pragma unroll
      for (int mi = 0; mi < 2; ++mi)
        #pragma unroll
        for (int ni = 0; ni < 2; ++ni)
          #pragma unroll
          for (int mj = 0; mj < 4; ++mj)
            #pragma unroll
            for (int nj = 0; nj < 4; ++nj)
              acc[mi][ni][mj][nj] += am[mi][mj] * bn[ni][nj];
    }
  }

  const float4 bi0 = *(const float4*)(bias + n0 + tx * 4);
  const float4 bi1 = *(const float4*)(bias + n0 + tx * 4 + 64);
  const float bb[2][4] = {{bi0.x, bi0.y, bi0.z, bi0.w}, {bi1.x, bi1.y, bi1.z, bi1.w}};

  #pragma unroll
  for (int mi = 0; mi < 2; ++mi)
    #pragma unroll
    for (int mj = 0; mj < 4; ++mj) {
      const int m = m0 + mi * 64 + ty * 4 + mj;
      #pragma unroll
      for (int ni = 0; ni < 2; ++ni) {
        float4 o;
        o.x = alpha * acc[mi][ni][mj][0] + bb[ni][0];
        o.y = alpha * acc[mi][ni][mj][1] + bb[ni][1];
        o.z = alpha * acc[mi][ni][mj][2] + bb[ni][2];
        o.w = alpha * acc[mi][ni][mj][3] + bb[ni][3];
        *(float4*)(C + (size_t)m * N + n0 + ni * 64 + tx * 4) = o;
      }
    }
}

// ------------------------------------------------------------------
__global__ __launch_bounds__(512) void esq_kernel(const float* __restrict__ emb,
                                                  float* __restrict__ esq)
{
  const int k = threadIdx.x;
  float s = 0.0f;
  for (int d = 0; d < DD; ++d) { const float v = emb[(size_t)d * KC + k]; s += v * v; }
  esq[k] = s;
}

__global__ __launch_bounds__(256) void transpose_kernel(const float* __restrict__ emb,
                                                        float* __restrict__ embT)
{
  const int t = blockIdx.x * 256 + threadIdx.x;
  const int d = t & (DD - 1);
  const int k = t >> 10;
  embT[t] = emb[(size_t)d * KC + k];
}

// ------------------------------------------------------------------
__global__ __launch_bounds__(64) void argmin_kernel(const float* __restrict__ S,
                                                    int* __restrict__ idx,
                                                    int* __restrict__ cnt)
{
  const int i = blockIdx.x;
  const int lane = threadIdx.x;
  const float* row = S + (size_t)i * KC;
  float best = 3.4e38f;
  int   bi   = 0x7fffffff;
  for (int k = lane; k < KC; k += 64) {
    const float v = row[k];
    if (v < best) { best = v; bi = k; }
  }
  #pragma unroll
  for (int off = 32; off > 0; off >>= 1) {
    const float ov = __shfl_down(best, off);
    const int   oi = __shfl_down(bi, off);
    if (ov < best || (ov == best && oi < bi)) { best = ov; bi = oi; }
  }
  if (lane == 0) { idx[i] = bi; atomicAdd(cnt + bi, 1); }
}

// ------------------------------------------------------------------
// exclusive prefix over cnt -> offs, and init cursor = offs
// ------------------------------------------------------------------
__global__ __launch_bounds__(512) void prefix_kernel(const int* __restrict__ cnt,
                                                     int* __restrict__ offs,
                                                     int* __restrict__ cursor)
{
  __shared__ int s[512];
  const int t = threadIdx.x;
  s[t] = cnt[t]; __syncthreads();
  for (int d = 1; d < 512; d <<= 1) {
    const int v = (t >= d) ? s[t - d] : 0;
    __syncthreads();
    s[t] += v;
    __syncthreads();
  }
  const int excl = (t == 0) ? 0 : s[t - 1];
  offs[t] = excl;
  cursor[t] = excl;
}

__global__ __launch_bounds__(256) void scatter_kernel(const int* __restrict__ idx,
                                                      int* __restrict__ cursor,
                                                      int* __restrict__ rows)
{
  const int i = blockIdx.x * 256 + threadIdx.x;
  const int k = idx[i];
  const int slot = atomicAdd(cursor + k, 1);
  rows[slot] = i;
}

// ------------------------------------------------------------------
__global__ __launch_bounds__(512) void finalize_cs_kernel(const int* __restrict__ cnt,
    const float* __restrict__ ecs,
    float* __restrict__ out_perp, float* __restrict__ out_cs, float* __restrict__ ws_cs)
{
  const int t = threadIdx.x;
  __shared__ float red[512];
  const float c  = (float)cnt[t];
  const float cs = F_DECAY * ecs[t] + F_OMD * c;
  red[t] = cs; __syncthreads();
  for (int s = 256; s > 0; s >>= 1) { if (t < s) red[t] += red[t + s]; __syncthreads(); }
  const float n = red[0]; __syncthreads();
  const float css = (cs + F_EPS) / (n + (float)KC * F_EPS) * n;
  out_cs[t] = css;
  ws_cs[t]  = css;
  const float p = c * (1.0f / (float)BB);
  red[t] = p * logf(p + 1e-10f); __syncthreads();
  for (int s = 256; s > 0; s >>= 1) { if (t < s) red[t] += red[t + s]; __syncthreads(); }
  if (t == 0) *out_perp = expf(-red[0]);
}

__global__ void finalize_loss_kernel(const float* __restrict__ lsum,
                                     float* __restrict__ out_loss)
{
  *out_loss = F_CC * lsum[0] * (1.0f / ((float)BB * (float)DD));
}

// ------------------------------------------------------------------
// new_embeddings via sorted per-cluster row lists: block (k, d-chunk)
// ------------------------------------------------------------------
__global__ __launch_bounds__(256) void dw2_kernel(const int* __restrict__ rows,
    const int* __restrict__ offs, const int* __restrict__ cnt,
    const float* __restrict__ z, const float* __restrict__ edw,
    const float* __restrict__ wcs, float* __restrict__ out_emb)
{
  const int k = blockIdx.x;
  const int d = blockIdx.y * 256 + threadIdx.x;
  const int o = offs[k];
  const int c = cnt[k];
  float a = 0.0f;
  for (int r = 0; r < c; ++r)
    a += z[(size_t)rows[o + r] * DD + d];
  out_emb[(size_t)d * KC + k] = (F_DECAY * edw[(size_t)d * KC + k] + F_OMD * a) / wcs[k];
}

// ------------------------------------------------------------------
// q_st gather IN PLACE over z; accumulates sum((q - z)^2) into lsum.
// ------------------------------------------------------------------
__global__ __launch_bounds__(256) void gather_kernel(const int* __restrict__ idx,
    const float* __restrict__ embT, float* zq, float* __restrict__ lsum)
{
  const int i = blockIdx.x;
  const int t = threadIdx.x;
  const int id = idx[i];
  const float4 q  = *(const float4*)(embT + (size_t)id * DD + t * 4);
  const float4 zv = *(const float4*)(zq   + (size_t)i  * DD + t * 4);
  *(float4*)(zq + (size_t)i * DD + t * 4) = q;
  const float dx = q.x - zv.x, dy = q.y - zv.y, dz = q.z - zv.z, dw = q.w - zv.w;
  float s = dx * dx + dy * dy + dz * dz + dw * dw;

  __shared__ float red[256];
  red[t] = s; __syncthreads();
  for (int st = 128; st > 0; st >>= 1) { if (t < st) red[t] += red[t + st]; __syncthreads(); }
  if (t == 0) atomicAdd(lsum, red[0]);
}

// ------------------------------------------------------------------
extern "C" void kernel_launch(void* const* d_in, const int* in_sizes, int n_in,
                              void* d_out, int out_size, void* d_ws, size_t ws_size,
                              hipStream_t stream)
{
  const float* obs  = (const float*)d_in[0];
  const float* act  = (const float*)d_in[1];
  const float* nobs = (const float*)d_in[2];
  const float* rew  = (const float*)d_in[3];
  const float* term = (const float*)d_in[4];
  const float* w0 = (const float*)d_in[5];  const float* b0 = (const float*)d_in[6];
  const float* w1 = (const float*)d_in[7];  const float* b1 = (const float*)d_in[8];
  const float* w2 = (const float*)d_in[9];  const float* b2 = (const float*)d_in[10];
  const float* w3 = (const float*)d_in[11]; const float* b3 = (const float*)d_in[12];
  const float* wl = (const float*)d_in[13]; const float* bl = (const float*)d_in[14];
  const float* emb = (const float*)d_in[15];
  const float* ecs = (const float*)d_in[16];
  const float* edw = (const float*)d_in[17];

  // ---- workspace layout (floats) — 72.8 MiB, proven to fit ----
  float* ws   = (float*)d_ws;
  float* bufX = ws;                               // MC*K0P  = 2,293,760
  float* bufA = bufX + (size_t)MC * K0P;          // MC*HH   = 8,388,608
  float* bufB = bufA + (size_t)MC * HH;           // MC*HH   = 8,388,608
  // post-MLP overlays:
  float* S    = bufA;                             // BB*KC = 8,388,608 (exact fit)
  float* esq  = bufB;                             // KC
  float* embT = esq + KC;                         // KC*DD
  int*   idx  = (int*)(embT + (size_t)KC * DD);   // BB
  int*   cnt  = idx + BB;                         // KC
  float* lsum = (float*)(cnt + KC);               // 1
  float* wcs  = lsum + 1;                         // KC
  int*   offs = (int*)(wcs + KC);                 // KC
  int*   curs = offs + KC;                        // KC
  int*   rows = curs + KC;                        // BB   (tail << bufB size)

  float* out      = (float*)d_out;
  float* zq       = out;                          // z here; gather overwrites with q_st
  float* out_loss = out + (size_t)BB * DD;
  float* out_perp = out_loss + 1;
  float* out_emb  = out_perp + 1;
  float* out_cs   = out_emb + (size_t)DD * KC;

  const dim3 blk(256);

  // ---- MLP in batch chunks (emulated-fp32 MFMA GEMMs) ----
  for (int c = 0; c < NCH; ++c) {
    const size_t c0 = (size_t)c * MC;
    build_x0_kernel<<<dim3(MC), blk, 0, stream>>>(obs + c0 * NOBS, act + c0 * NACT,
                                                  nobs + c0 * NOBS, rew + c0, term + c0, bufX);
    gemm_bf16x3_kernel<true ><<<dim3(HH/128, MC/128), blk, 0, stream>>>(bufX, w0, b0, bufA, MC, HH, K0P, DIN);
    gemm_bf16x3_kernel<true ><<<dim3(HH/128, MC/128), blk, 0, stream>>>(bufA, w1, b1, bufB, MC, HH, HH,  HH);
    gemm_bf16x3_kernel<true ><<<dim3(HH/128, MC/128), blk, 0, stream>>>(bufB, w2, b2, bufA, MC, HH, HH,  HH);
    gemm_bf16x3_kernel<true ><<<dim3(HH/128, MC/128), blk, 0, stream>>>(bufA, w3, b3, bufB, MC, HH, HH,  HH);
    gemm_bf16x3_kernel<false><<<dim3(DD/128, MC/128), blk, 0, stream>>>(bufB, wl, bl, zq + c0 * DD, MC, DD, HH, HH);
  }

  // ---- VQ phase ----
  init_kernel<<<1, 512, 0, stream>>>(cnt, lsum);
  esq_kernel<<<1, 512, 0, stream>>>(emb, esq);
  sgemm_kernel<<<dim3(KC/128, BB/128), blk, 0, stream>>>(zq, emb, esq, S, BB, KC, DD, DD, -2.0f);
  argmin_kernel<<<dim3(BB), dim3(64), 0, stream>>>(S, idx, cnt);
  prefix_kernel<<<1, 512, 0, stream>>>(cnt, offs, curs);
  scatter_kernel<<<dim3(BB/256), blk, 0, stream>>>(idx, curs, rows);
  finalize_cs_kernel<<<1, 512, 0, stream>>>(cnt, ecs, out_perp, out_cs, wcs);
  dw2_kernel<<<dim3(KC, DD/256), blk, 0, stream>>>(rows, offs, cnt, zq, edw, wcs, out_emb);
  transpose_kernel<<<dim3((KC*DD)/256), blk, 0, stream>>>(emb, embT);
  gather_kernel<<<dim3(BB), blk, 0, stream>>>(idx, embT, zq, lsum);
  finalize_loss_kernel<<<1, 1, 0, stream>>>(lsum, out_loss);
}

// Round 4
// 15454.182 us; speedup vs baseline: 1.9409x; 1.1712x over previous
//
#include <hip/hip_runtime.h>
#include <math.h>

// Problem constants (match reference)
#define BB   16384
#define NOBS 512
#define NACT 64
#define DIN  1090      // 512+64+512+1+1
#define K0P  1120      // DIN padded to multiple of 32 (zeros)
#define HH   4096
#define DD   1024
#define KC   512

#define MC   2048      // batch chunk rows for the MLP
#define NCH  (BB / MC) // 8 chunks

#define F_DECAY 0.99f
#define F_OMD   0.01f
#define F_CC    0.25f
#define F_EPS   1e-5f

using s8v  = __attribute__((ext_vector_type(8))) short;   // 8 bf16 (4 VGPRs) MFMA A/B frag
using s4v  = __attribute__((ext_vector_type(4))) short;   // 4 bf16 (8B LDS store)
using f4v  = __attribute__((ext_vector_type(4))) float;   // MFMA C/D frag

// ---- fp32 -> bf16 (RNE) bit ops + exact 3-way split ----
static __device__ inline unsigned short f2bf(float f) {
  unsigned u = __float_as_uint(f);
  u += 0x7fff + ((u >> 16) & 1);
  return (unsigned short)(u >> 16);
}
static __device__ inline float bf2f(unsigned short h) {
  return __uint_as_float(((unsigned)h) << 16);
}
static __device__ inline void split3(float x, unsigned short& h, unsigned short& m,
                                     unsigned short& l) {
  h = f2bf(x);  const float r1 = x - bf2f(h);   // exact
  m = f2bf(r1); const float r2 = r1 - bf2f(m);  // exact
  l = f2bf(r2);
}

// ------------------------------------------------------------------
// Build one chunk of X0 = hstack(obs, action, next_obs, reward, term), padded.
// ------------------------------------------------------------------
__global__ __launch_bounds__(256) void build_x0_kernel(
    const float* __restrict__ obs, const float* __restrict__ act,
    const float* __restrict__ nobs, const float* __restrict__ rew,
    const float* __restrict__ term, float* __restrict__ X0)
{
  const int i = blockIdx.x;
  const int t = threadIdx.x;
  float* row = X0 + (size_t)i * K0P;
  for (int c = t; c < K0P; c += 256) {
    float v;
    if (c < NOBS)                 v = obs[(size_t)i * NOBS + c];
    else if (c < NOBS + NACT)     v = act[(size_t)i * NACT + (c - NOBS)];
    else if (c < 2*NOBS + NACT)   v = nobs[(size_t)i * NOBS + (c - NOBS - NACT)];
    else if (c == 1088)           v = rew[i];
    else if (c == 1089)           v = term[i];
    else                          v = 0.0f;
    row[c] = v;
  }
}

__global__ void init_kernel(int* __restrict__ cnt, float* __restrict__ lsum)
{
  const int t = threadIdx.x;
  if (t < KC) cnt[t] = 0;
  if (t == 0) *lsum = 0.0f;
}

__global__ __launch_bounds__(256) void zero_kernel(float* __restrict__ p, int n)
{
  const int i = blockIdx.x * 256 + threadIdx.x;
  if (i < n) p[i] = 0.0f;
}

// ------------------------------------------------------------------
// Emulated-fp32 GEMM via bf16x3 split + MFMA (6 products):
// C[m,n] = act( sum_k A[m,k]*W[k,n] + bias[n] )
// A: [M,K] fp32 row-major, W: [K,N] fp32 row-major (rows >= Kreal read as 0).
// BM=BN=128, BK=32, 256 threads (4 waves, 2x2), wave tile 64x64 =
// 4x4 of 16x16x32 MFMA tiles. LDS: [comp][kgroup][row][8] bf16, k-contiguous
// per lane (16B/lane ds_read_b128, conflict-free).
// ------------------------------------------------------------------
template<bool RELU>
__global__ __launch_bounds__(256, 2) void gemm_bf16x3_kernel(
    const float* __restrict__ A, const float* __restrict__ W,
    const float* __restrict__ bias, float* __restrict__ C,
    int M, int N, int K, int Kreal)
{
  __shared__ __align__(16) short Alds[3][4][128][8];   // 24 KB
  __shared__ __align__(16) short Blds[3][4][128][8];   // 24 KB

  const int tid = threadIdx.x;
  const int n0 = blockIdx.x * 128;
  const int m0 = blockIdx.y * 128;

  const int sam = tid >> 1;          // A row 0..127
  const int sah = tid & 1;           // A k-half (16 floats each)
  const int sbn = tid & 127;         // B col 0..127
  const int sbq = tid >> 7;          // B k-half

  const int lane = tid & 63;
  const int wv   = tid >> 6;             // wave 0..3 (2x2)
  const int wmo  = (wv >> 1) * 64;
  const int wno  = (wv & 1) * 64;
  const int lm   = lane & 15;            // m (A) / n (B) / col (C)
  const int kg   = lane >> 4;            // k-group 0..3 (8 k each)

  f4v acc[4][4];
  #pragma unroll
  for (int a = 0; a < 4; ++a)
    #pragma unroll
    for (int b = 0; b < 4; ++b) acc[a][b] = (f4v)0.0f;

  for (int k0 = 0; k0 < K; k0 += 32) {
    float4 av[4];
    #pragma unroll
    for (int q = 0; q < 4; ++q)
      av[q] = *(const float4*)(A + (size_t)(m0 + sam) * K + k0 + sah * 16 + q * 4);
    float bv[16];
    #pragma unroll
    for (int i = 0; i < 16; ++i) {
      const int kk = k0 + sbq * 16 + i;
      bv[i] = (kk < Kreal) ? W[(size_t)kk * N + n0 + sbn] : 0.0f;
    }

    __syncthreads();

    #pragma unroll
    for (int q = 0; q < 4; ++q) {
      const float xs[4] = {av[q].x, av[q].y, av[q].z, av[q].w};
      s4v hh, mm, ll;
      #pragma unroll
      for (int j = 0; j < 4; ++j) {
        unsigned short h, m, l; split3(xs[j], h, m, l);
        hh[j] = (short)h; mm[j] = (short)m; ll[j] = (short)l;
      }
      const int kgi = sah * 2 + (q >> 1);
      const int j0  = (q & 1) * 4;
      *(s4v*)&Alds[0][kgi][sam][j0] = hh;
      *(s4v*)&Alds[1][kgi][sam][j0] = mm;
      *(s4v*)&Alds[2][kgi][sam][j0] = ll;
    }
    unsigned short bh[16], bm[16], bl[16];
    #pragma unroll
    for (int i = 0; i < 16; ++i) split3(bv[i], bh[i], bm[i], bl[i]);
    #pragma unroll
    for (int g = 0; g < 2; ++g) {
      s8v vh, vm, vl;
      #pragma unroll
      for (int j = 0; j < 8; ++j) {
        vh[j] = (short)bh[g * 8 + j]; vm[j] = (short)bm[g * 8 + j]; vl[j] = (short)bl[g * 8 + j];
      }
      const int kgi = sbq * 2 + g;
      *(s8v*)&Blds[0][kgi][sbn][0] = vh;
      *(s8v*)&Blds[1][kgi][sbn][0] = vm;
      *(s8v*)&Blds[2][kgi][sbn][0] = vl;
    }
    __syncthreads();

    s8v bf[3][4];
    #pragma unroll
    for (int nt = 0; nt < 4; ++nt) {
      bf[0][nt] = *(const s8v*)&Blds[0][kg][wno + nt * 16 + lm][0];
      bf[1][nt] = *(const s8v*)&Blds[1][kg][wno + nt * 16 + lm][0];
      bf[2][nt] = *(const s8v*)&Blds[2][kg][wno + nt * 16 + lm][0];
    }
    #pragma unroll
    for (int mt = 0; mt < 4; ++mt) {
      const s8v ah = *(const s8v*)&Alds[0][kg][wmo + mt * 16 + lm][0];
      const s8v am = *(const s8v*)&Alds[1][kg][wmo + mt * 16 + lm][0];
      const s8v al = *(const s8v*)&Alds[2][kg][wmo + mt * 16 + lm][0];
      #pragma unroll
      for (int nt = 0; nt < 4; ++nt) {
        f4v a = acc[mt][nt];
        a = __builtin_amdgcn_mfma_f32_16x16x32_bf16(ah, bf[0][nt], a, 0, 0, 0); // hi*hi
        a = __builtin_amdgcn_mfma_f32_16x16x32_bf16(ah, bf[1][nt], a, 0, 0, 0); // hi*mid
        a = __builtin_amdgcn_mfma_f32_16x16x32_bf16(am, bf[0][nt], a, 0, 0, 0); // mid*hi
        a = __builtin_amdgcn_mfma_f32_16x16x32_bf16(ah, bf[2][nt], a, 0, 0, 0); // hi*lo
        a = __builtin_amdgcn_mfma_f32_16x16x32_bf16(al, bf[0][nt], a, 0, 0, 0); // lo*hi
        a = __builtin_amdgcn_mfma_f32_16x16x32_bf16(am, bf[1][nt], a, 0, 0, 0); // mid*mid
        acc[mt][nt] = a;
      }
    }
  }

  float bias_v[4];
  #pragma unroll
  for (int nt = 0; nt < 4; ++nt) bias_v[nt] = bias[n0 + wno + nt * 16 + lm];

  #pragma unroll
  for (int mt = 0; mt < 4; ++mt)
    #pragma unroll
    for (int nt = 0; nt < 4; ++nt) {
      const int n = n0 + wno + nt * 16 + lm;
      #pragma unroll
      for (int r = 0; r < 4; ++r) {
        const int m = m0 + wmo + mt * 16 + kg * 4 + r;
        float v = acc[mt][nt][r] + bias_v[nt];
        if (RELU) v = fmaxf(v, 0.0f);
        C[(size_t)m * N + n] = v;
      }
    }
}

// ------------------------------------------------------------------
// fp32 vector GEMM (scores GEMM only)
// ------------------------------------------------------------------
__global__ __launch_bounds__(256) void sgemm_kernel(
    const float* __restrict__ A, const float* __restrict__ W,
    const float* __restrict__ bias, float* __restrict__ C,
    int M, int N, int K, int Kreal, float alpha)
{
  __shared__ float As[16][128];
  __shared__ float Bs[16][128];

  const int tid = threadIdx.x;
  const int n0 = blockIdx.x * 128;
  const int m0 = blockIdx.y * 128;

  const int ar = tid & 63;
  const int ak = (tid >> 6) << 2;
  const int bk = tid >> 5;
  const int bc = (tid & 31) << 2;
  const int tx = tid & 15;
  const int ty = tid >> 4;

  float acc[2][2][4][4];
  #pragma unroll
  for (int a = 0; a < 2; ++a)
    #pragma unroll
    for (int b = 0; b < 2; ++b)
      #pragma unroll
      for (int c = 0; c < 4; ++c)
        #pragma unroll
        for (int d = 0; d < 4; ++d) acc[a][b][c][d] = 0.0f;

  const float4 zero4 = make_float4(0.f, 0.f, 0.f, 0.f);

  for (int k0 = 0; k0 < K; k0 += 16) {
    float4 a0 = *(const float4*)(A + (size_t)(m0 + ar) * K + k0 + ak);
    float4 a1 = *(const float4*)(A + (size_t)(m0 + ar + 64) * K + k0 + ak);
    const int kr0 = k0 + bk, kr1 = k0 + bk + 8;
    float4 b0 = (kr0 < Kreal) ? *(const float4*)(W + (size_t)kr0 * N + n0 + bc) : zero4;
    float4 b1 = (kr1 < Kreal) ? *(const float4*)(W + (size_t)kr1 * N + n0 + bc) : zero4;

    __syncthreads();
    As[ak + 0][ar] = a0.x; As[ak + 1][ar] = a0.y;
    As[ak + 2][ar] = a0.z; As[ak + 3][ar] = a0.w;
    As[ak + 0][ar + 64] = a1.x; As[ak + 1][ar + 64] = a1.y;
    As[ak + 2][ar + 64] = a1.z; As[ak + 3][ar + 64] = a1.w;
    *(float4*)&Bs[bk][bc]     = b0;
    *(float4*)&Bs[bk + 8][bc] = b1;
    __syncthreads();

    #pragma unroll
    for (int kk = 0; kk < 16; ++kk) {
      const float4 av0 = *(const float4*)&As[kk][ty * 4];
      const float4 av1 = *(const float4*)&As[kk][ty * 4 + 64];
      const float4 bv0 = *(const float4*)&Bs[kk][tx * 4];
      const float4 bv1 = *(const float4*)&Bs[kk][tx * 4 + 64];
      const float am[2][4] = {{av0.x, av0.y, av0.z, av0.w}, {av1.x, av1.y, av1.z, av1.w}};
      const float bn[2][4] = {{bv0.x, bv0.y, bv0.z, bv0.w}, {bv1.x, bv1.y, bv1.z, bv1.w}};
      #pragma unroll
      for (int mi = 0; mi < 2; ++mi)
        #pragma unroll
        for (int ni = 0; ni < 2; ++ni)
          #pragma unroll
          for (int mj = 0; mj < 4; ++mj)
            #pragma unroll
            for (int nj = 0; nj < 4; ++nj)
              acc[mi][ni][mj][nj] += am[mi][mj] * bn[ni][nj];
    }
  }

  const float4 bi0 = *(const float4*)(bias + n0 + tx * 4);
  const float4 bi1 = *(const float4*)(bias + n0 + tx * 4 + 64);
  const float bb[2][4] = {{bi0.x, bi0.y, bi0.z, bi0.w}, {bi1.x, bi1.y, bi1.z, bi1.w}};

  #pragma unroll
  for (int mi = 0; mi < 2; ++mi)
    #pragma unroll
    for (int mj = 0; mj < 4; ++mj) {
      const int m = m0 + mi * 64 + ty * 4 + mj;
      #pragma unroll
      for (int ni = 0; ni < 2; ++ni) {
        float4 o;
        o.x = alpha * acc[mi][ni][mj][0] + bb[ni][0];
        o.y = alpha * acc[mi][ni][mj][1] + bb[ni][1];
        o.z = alpha * acc[mi][ni][mj][2] + bb[ni][2];
        o.w = alpha * acc[mi][ni][mj][3] + bb[ni][3];
        *(float4*)(C + (size_t)m * N + n0 + ni * 64 + tx * 4) = o;
      }
    }
}

// ------------------------------------------------------------------
__global__ __launch_bounds__(512) void esq_kernel(const float* __restrict__ emb,
                                                  float* __restrict__ esq)
{
  const int k = threadIdx.x;
  float s = 0.0f;
  for (int d = 0; d < DD; ++d) { const float v = emb[(size_t)d * KC + k]; s += v * v; }
  esq[k] = s;
}

__global__ __launch_bounds__(256) void transpose_kernel(const float* __restrict__ emb,
                                                        float* __restrict__ embT)
{
  const int t = blockIdx.x * 256 + threadIdx.x;
  const int d = t & (DD - 1);
  const int k = t >> 10;
  embT[t] = emb[(size_t)d * KC + k];
}

// ------------------------------------------------------------------
__global__ __launch_bounds__(64) void argmin_kernel(const float* __restrict__ S,
                                                    int* __restrict__ idx,
                                                    int* __restrict__ cnt)
{
  const int i = blockIdx.x;
  const int lane = threadIdx.x;
  const float* row = S + (size_t)i * KC;
  float best = 3.4e38f;
  int   bi   = 0x7fffffff;
  for (int k = lane; k < KC; k += 64) {
    const float v = row[k];
    if (v < best) { best = v; bi = k; }
  }
  #pragma unroll
  for (int off = 32; off > 0; off >>= 1) {
    const float ov = __shfl_down(best, off);
    const int   oi = __shfl_down(bi, off);
    if (ov < best || (ov == best && oi < bi)) { best = ov; bi = oi; }
  }
  if (lane == 0) { idx[i] = bi; atomicAdd(cnt + bi, 1); }
}

// ------------------------------------------------------------------
__global__ __launch_bounds__(512) void prefix_kernel(const int* __restrict__ cnt,
                                                     int* __restrict__ offs,
                                                     int* __restrict__ cursor)
{
  __shared__ int s[512];
  const int t = threadIdx.x;
  s[t] = cnt[t]; __syncthreads();
  for (int d = 1; d < 512; d <<= 1) {
    const int v = (t >= d) ? s[t - d] : 0;
    __syncthreads();
    s[t] += v;
    __syncthreads();
  }
  const int excl = (t == 0) ? 0 : s[t - 1];
  offs[t] = excl;
  cursor[t] = excl;
}

__global__ __launch_bounds__(256) void scatter_kernel(const int* __restrict__ idx,
                                                      int* __restrict__ cursor,
                                                      int* __restrict__ rows)
{
  const int i = blockIdx.x * 256 + threadIdx.x;
  const int k = idx[i];
  const int slot = atomicAdd(cursor + k, 1);
  rows[slot] = i;
}

// ------------------------------------------------------------------
__global__ __launch_bounds__(512) void finalize_cs_kernel(const int* __restrict__ cnt,
    const float* __restrict__ ecs,
    float* __restrict__ out_perp, float* __restrict__ out_cs, float* __restrict__ ws_cs)
{
  const int t = threadIdx.x;
  __shared__ float red[512];
  const float c  = (float)cnt[t];
  const float cs = F_DECAY * ecs[t] + F_OMD * c;
  red[t] = cs; __syncthreads();
  for (int s = 256; s > 0; s >>= 1) { if (t < s) red[t] += red[t + s]; __syncthreads(); }
  const float n = red[0]; __syncthreads();
  const float css = (cs + F_EPS) / (n + (float)KC * F_EPS) * n;
  out_cs[t] = css;
  ws_cs[t]  = css;
  const float p = c * (1.0f / (float)BB);
  red[t] = p * logf(p + 1e-10f); __syncthreads();
  for (int s = 256; s > 0; s >>= 1) { if (t < s) red[t] += red[t + s]; __syncthreads(); }
  if (t == 0) *out_perp = expf(-red[0]);
}

__global__ void finalize_loss_kernel(const float* __restrict__ lsum,
                                     float* __restrict__ out_loss)
{
  *out_loss = F_CC * lsum[0] * (1.0f / ((float)BB * (float)DD));
}

// ------------------------------------------------------------------
// dw partial sums: block (k, segment s) sums rows [s*256,(s+1)*256) of
// cluster k into registers (4 d-positions/thread), one atomicAdd per
// (d,k) partial. Worst-case serial chain = 256 rows (was 16384).
// ------------------------------------------------------------------
__global__ __launch_bounds__(256) void dw3_partial_kernel(const int* __restrict__ rows,
    const int* __restrict__ offs, const int* __restrict__ cnt,
    const float* __restrict__ z, float* __restrict__ dwacc)
{
  const int k = blockIdx.x;
  const int s = blockIdx.y;
  const int c = cnt[k];
  const int begin = s * 256;
  if (begin >= c) return;
  const int nrows = min(c - begin, 256);
  const int o = offs[k] + begin;
  const int t = threadIdx.x;

  __shared__ int rlist[256];
  if (t < nrows) rlist[t] = rows[o + t];
  __syncthreads();

  float a0 = 0.f, a1 = 0.f, a2 = 0.f, a3 = 0.f;
  for (int r = 0; r < nrows; ++r) {
    const float* zr = z + (size_t)rlist[r] * DD;
    a0 += zr[t]; a1 += zr[t + 256]; a2 += zr[t + 512]; a3 += zr[t + 768];
  }
  atomicAdd(&dwacc[(size_t)(t      ) * KC + k], a0);
  atomicAdd(&dwacc[(size_t)(t + 256) * KC + k], a1);
  atomicAdd(&dwacc[(size_t)(t + 512) * KC + k], a2);
  atomicAdd(&dwacc[(size_t)(t + 768) * KC + k], a3);
}

__global__ __launch_bounds__(256) void dw3_final_kernel(const float* __restrict__ dwacc,
    const float* __restrict__ edw, const float* __restrict__ wcs,
    float* __restrict__ out_emb)
{
  const size_t t = (size_t)blockIdx.x * 256 + threadIdx.x;  // t = d*KC + k
  const int k = (int)(t & (KC - 1));
  out_emb[t] = (F_DECAY * edw[t] + F_OMD * dwacc[t]) / wcs[k];
}

// ------------------------------------------------------------------
// q_st gather IN PLACE over z; accumulates sum((q - z)^2) into lsum.
// ------------------------------------------------------------------
__global__ __launch_bounds__(256) void gather_kernel(const int* __restrict__ idx,
    const float* __restrict__ embT, float* zq, float* __restrict__ lsum)
{
  const int i = blockIdx.x;
  const int t = threadIdx.x;
  const int id = idx[i];
  const float4 q  = *(const float4*)(embT + (size_t)id * DD + t * 4);
  const float4 zv = *(const float4*)(zq   + (size_t)i  * DD + t * 4);
  *(float4*)(zq + (size_t)i * DD + t * 4) = q;
  const float dx = q.x - zv.x, dy = q.y - zv.y, dz = q.z - zv.z, dw = q.w - zv.w;
  float s = dx * dx + dy * dy + dz * dz + dw * dw;

  __shared__ float red[256];
  red[t] = s; __syncthreads();
  for (int st = 128; st > 0; st >>= 1) { if (t < st) red[t] += red[t + st]; __syncthreads(); }
  if (t == 0) atomicAdd(lsum, red[0]);
}

// ------------------------------------------------------------------
extern "C" void kernel_launch(void* const* d_in, const int* in_sizes, int n_in,
                              void* d_out, int out_size, void* d_ws, size_t ws_size,
                              hipStream_t stream)
{
  const float* obs  = (const float*)d_in[0];
  const float* act  = (const float*)d_in[1];
  const float* nobs = (const float*)d_in[2];
  const float* rew  = (const float*)d_in[3];
  const float* term = (const float*)d_in[4];
  const float* w0 = (const float*)d_in[5];  const float* b0 = (const float*)d_in[6];
  const float* w1 = (const float*)d_in[7];  const float* b1 = (const float*)d_in[8];
  const float* w2 = (const float*)d_in[9];  const float* b2 = (const float*)d_in[10];
  const float* w3 = (const float*)d_in[11]; const float* b3 = (const float*)d_in[12];
  const float* wl = (const float*)d_in[13]; const float* bl = (const float*)d_in[14];
  const float* emb = (const float*)d_in[15];
  const float* ecs = (const float*)d_in[16];
  const float* edw = (const float*)d_in[17];

  // ---- workspace layout (floats) — 72.8 MiB, proven to fit ----
  float* ws   = (float*)d_ws;
  float* bufX = ws;                               // MC*K0P  = 2,293,760
  float* bufA = bufX + (size_t)MC * K0P;          // MC*HH   = 8,388,608
  float* bufB = bufA + (size_t)MC * HH;           // MC*HH   = 8,388,608
  // post-MLP overlays:
  float* S    = bufA;                             // BB*KC = 8,388,608 (exact fit)
  float* esq  = bufB;                             // KC
  float* embT = esq + KC;                         // KC*DD
  int*   idx  = (int*)(embT + (size_t)KC * DD);   // BB
  int*   cnt  = idx + BB;                         // KC
  float* lsum = (float*)(cnt + KC);               // 1
  float* wcs  = lsum + 1;                         // KC
  int*   offs = (int*)(wcs + KC);                 // KC
  int*   curs = offs + KC;                        // KC
  int*   rows = curs + KC;                        // BB
  float* dwacc= (float*)(rows + BB);              // DD*KC  (tail total ~1.08M < 8.38M)

  float* out      = (float*)d_out;
  float* zq       = out;                          // z here; gather overwrites with q_st
  float* out_loss = out + (size_t)BB * DD;
  float* out_perp = out_loss + 1;
  float* out_emb  = out_perp + 1;
  float* out_cs   = out_emb + (size_t)DD * KC;

  const dim3 blk(256);

  // ---- MLP in batch chunks (emulated-fp32 MFMA GEMMs) ----
  for (int c = 0; c < NCH; ++c) {
    const size_t c0 = (size_t)c * MC;
    build_x0_kernel<<<dim3(MC), blk, 0, stream>>>(obs + c0 * NOBS, act + c0 * NACT,
                                                  nobs + c0 * NOBS, rew + c0, term + c0, bufX);
    gemm_bf16x3_kernel<true ><<<dim3(HH/128, MC/128), blk, 0, stream>>>(bufX, w0, b0, bufA, MC, HH, K0P, DIN);
    gemm_bf16x3_kernel<true ><<<dim3(HH/128, MC/128), blk, 0, stream>>>(bufA, w1, b1, bufB, MC, HH, HH,  HH);
    gemm_bf16x3_kernel<true ><<<dim3(HH/128, MC/128), blk, 0, stream>>>(bufB, w2, b2, bufA, MC, HH, HH,  HH);
    gemm_bf16x3_kernel<true ><<<dim3(HH/128, MC/128), blk, 0, stream>>>(bufA, w3, b3, bufB, MC, HH, HH,  HH);
    gemm_bf16x3_kernel<false><<<dim3(DD/128, MC/128), blk, 0, stream>>>(bufB, wl, bl, zq + c0 * DD, MC, DD, HH, HH);
  }

  // ---- VQ phase ----
  init_kernel<<<1, 512, 0, stream>>>(cnt, lsum);
  zero_kernel<<<dim3((DD * KC) / 256), blk, 0, stream>>>(dwacc, DD * KC);
  esq_kernel<<<1, 512, 0, stream>>>(emb, esq);
  sgemm_kernel<<<dim3(KC/128, BB/128), blk, 0, stream>>>(zq, emb, esq, S, BB, KC, DD, DD, -2.0f);
  argmin_kernel<<<dim3(BB), dim3(64), 0, stream>>>(S, idx, cnt);
  prefix_kernel<<<1, 512, 0, stream>>>(cnt, offs, curs);
  scatter_kernel<<<dim3(BB/256), blk, 0, stream>>>(idx, curs, rows);
  finalize_cs_kernel<<<1, 512, 0, stream>>>(cnt, ecs, out_perp, out_cs, wcs);
  dw3_partial_kernel<<<dim3(KC, BB/256), blk, 0, stream>>>(rows, offs, cnt, zq, dwacc);
  dw3_final_kernel<<<dim3((DD*KC)/256), blk, 0, stream>>>(dwacc, edw, wcs, out_emb);
  transpose_kernel<<<dim3((KC*DD)/256), blk, 0, stream>>>(emb, embT);
  gather_kernel<<<dim3(BB), blk, 0, stream>>>(idx, embT, zq, lsum);
  finalize_loss_kernel<<<1, 1, 0, stream>>>(lsum, out_loss);
}